// Round 1
// baseline (1640.610 us; speedup 1.0000x reference)
//
#include <hip/hip_runtime.h>
#include <stdint.h>

typedef unsigned long long u64;
#define NPTS 4096
#define KNN 20

__device__ __forceinline__ unsigned orderbits(float f) {
  unsigned u = __float_as_uint(f);
  return ((int)u < 0) ? ~u : (u | 0x80000000u);
}

__device__ __forceinline__ u64 shflxor64(u64 v, int m) {
  unsigned lo = __shfl_xor((unsigned)(v & 0xffffffffull), m, 64);
  unsigned hi = __shfl_xor((unsigned)(v >> 32), m, 64);
  return (((u64)hi) << 32) | lo;
}

// ---------------- Kernel 1: exact KNN via radix-select on (distbits, idx) ----
__global__ __launch_bounds__(256) void knn_kernel(const float* __restrict__ x,
                                                  int* __restrict__ knn_out) {
  __shared__ unsigned keys[NPTS];   // 16 KB ordered dist bits
  __shared__ unsigned hist[2048];   // 8 KB
  __shared__ unsigned wsum[4];
  __shared__ unsigned sBstar, sCnt, sCand;
  __shared__ u64 cand[256];

  const int tid = threadIdx.x;
  const int bid = blockIdx.x;
  const int b = bid >> 12;
  const int n = bid & 4095;
  const float* xb = x + (size_t)b * 3 * NPTS;
  const float xn0 = xb[n], xn1 = xb[NPTS + n], xn2 = xb[2 * NPTS + n];
  const float sqn = __fadd_rn(__fadd_rn(__fmul_rn(xn0, xn0), __fmul_rn(xn1, xn1)),
                              __fmul_rn(xn2, xn2));

  for (int i = tid; i < 2048; i += 256) hist[i] = 0;
  if (tid == 0) { sCnt = 0; sCand = 0; }
  __syncthreads();

  for (int m = tid; m < NPTS; m += 256) {
    float a0 = xb[m], a1 = xb[NPTS + m], a2 = xb[2 * NPTS + m];
    // match reference/np association exactly, no fma contraction:
    float inner = __fadd_rn(__fadd_rn(__fmul_rn(xn0, a0), __fmul_rn(xn1, a1)),
                            __fmul_rn(xn2, a2));
    float sqm = __fadd_rn(__fadd_rn(__fmul_rn(a0, a0), __fmul_rn(a1, a1)),
                          __fmul_rn(a2, a2));
    float d = __fadd_rn(__fsub_rn(sqn, __fmul_rn(2.0f, inner)), sqm);
    unsigned u = orderbits(d);
    keys[m] = u;
    atomicAdd(&hist[u >> 21], 1u);
  }
  __syncthreads();

  // block-wide prefix over 2048 buckets (8/thread) to find boundary bucket
  unsigned local = 0;
#pragma unroll
  for (int j = 0; j < 8; ++j) local += hist[tid * 8 + j];
  unsigned incl = local;
  const int lane = tid & 63, wid = tid >> 6;
  for (int off = 1; off < 64; off <<= 1) {
    unsigned v = __shfl_up(incl, off, 64);
    if (lane >= off) incl += v;
  }
  if (lane == 63) wsum[wid] = incl;
  __syncthreads();
  unsigned woff = 0;
  for (int w = 0; w < wid; ++w) woff += wsum[w];
  unsigned excl = woff + incl - local;
  if (excl < KNN && excl + local >= KNN) {
    unsigned cum = excl;
#pragma unroll
    for (int j = 0; j < 8; ++j) {
      unsigned c = hist[tid * 8 + j];
      if (cum + c >= KNN) { sBstar = tid * 8 + j; break; }
      cum += c;
    }
  }
  __syncthreads();

  const unsigned Bstar = sBstar;
  const int base = bid * KNN;
  for (int m = tid; m < NPTS; m += 256) {
    unsigned u = keys[m];
    unsigned bkt = u >> 21;
    if (bkt < Bstar) {
      unsigned p = atomicAdd(&sCnt, 1u);
      knn_out[base + p] = m;                 // order within the 20 is irrelevant
    } else if (bkt == Bstar) {
      unsigned p = atomicAdd(&sCand, 1u);
      if (p < 256) cand[p] = (((u64)u) << 32) | (unsigned)m;
    }
  }
  __syncthreads();
  const int nsel = (int)sCnt;
  const int ncand = min((int)sCand, 256);
  const int ntake = KNN - nsel;
  if (tid < 64) {  // single wave: iterative min-extract on boundary candidates
    volatile u64* vc = cand;
    for (int t = 0; t < ntake; ++t) {
      u64 mk = ~0ull;
      for (int i = tid; i < ncand; i += 64) { u64 v = vc[i]; if (v < mk) mk = v; }
      for (int off = 32; off; off >>= 1) { u64 o = shflxor64(mk, off); if (o < mk) mk = o; }
      if (tid == 0) knn_out[base + nsel + t] = (int)(unsigned)(mk & 0xffffffffull);
      for (int i = tid; i < ncand; i += 64) { if (vc[i] == mk) vc[i] = ~0ull; }
    }
  }
}

// ---------------- Kernel 2: edge MLP 6->64->128, max over K -----------------
// one wave per point; h stored TRANSPOSED as (B, N, 128) for coalescing
__global__ __launch_bounds__(64) void edge_kernel(
    const float* __restrict__ x, const int* __restrict__ knn,
    const float* __restrict__ W1, const float* __restrict__ b1,
    const float* __restrict__ W2, const float* __restrict__ b2,
    float* __restrict__ hT) {
  __shared__ __align__(16) float edgeL[KNN * 8];
  __shared__ __align__(16) float h1L[KNN * 64];
  const int lane = threadIdx.x;

  float w1r[6];
#pragma unroll
  for (int j = 0; j < 6; ++j) w1r[j] = W1[lane * 6 + j];
  const float b1r = b1[lane];
  float4 w2a[16], w2b[16];
  const float4* W2a4 = (const float4*)(W2 + (size_t)lane * 64);
  const float4* W2b4 = (const float4*)(W2 + (size_t)(lane + 64) * 64);
#pragma unroll
  for (int j = 0; j < 16; ++j) { w2a[j] = W2a4[j]; w2b[j] = W2b4[j]; }
  const float b2a = b2[lane], b2bv = b2[lane + 64];

  for (int it = 0; it < 8; ++it) {
    const int idx = blockIdx.x * 8 + it;
    const int b = idx >> 12, n = idx & 4095;
    const float* xb = x + (size_t)b * 3 * NPTS;
    const float c0 = xb[n], c1 = xb[NPTS + n], c2 = xb[2 * NPTS + n];
    if (lane < KNN) {
      int nb = knn[idx * KNN + lane];
      float a0 = xb[nb], a1 = xb[NPTS + nb], a2 = xb[2 * NPTS + nb];
      float* e = &edgeL[lane * 8];
      e[0] = c0; e[1] = c1; e[2] = c2;
      e[3] = a0 - c0; e[4] = a1 - c1; e[5] = a2 - c2;
    }
    __syncthreads();
#pragma unroll
    for (int k = 0; k < KNN; ++k) {   // h1: lane = channel, broadcast edge reads
      const float* e = &edgeL[k * 8];
      float acc = b1r;
      acc = fmaf(w1r[0], e[0], acc); acc = fmaf(w1r[1], e[1], acc);
      acc = fmaf(w1r[2], e[2], acc); acc = fmaf(w1r[3], e[3], acc);
      acc = fmaf(w1r[4], e[4], acc); acc = fmaf(w1r[5], e[5], acc);
      h1L[k * 64 + lane] = fmaxf(acc, 0.f);
    }
    __syncthreads();
    float ma = 0.f, mb = 0.f;           // relu folded into max (init 0)
    for (int k = 0; k < KNN; ++k) {
      const float4* h4 = (const float4*)&h1L[k * 64];
      float za0 = b2a, za1 = 0.f, zb0 = b2bv, zb1 = 0.f;
#pragma unroll
      for (int j = 0; j < 16; j += 2) {
        float4 v0 = h4[j], v1 = h4[j + 1];
        za0 = fmaf(w2a[j].x, v0.x, za0); za0 = fmaf(w2a[j].y, v0.y, za0);
        za0 = fmaf(w2a[j].z, v0.z, za0); za0 = fmaf(w2a[j].w, v0.w, za0);
        za1 = fmaf(w2a[j+1].x, v1.x, za1); za1 = fmaf(w2a[j+1].y, v1.y, za1);
        za1 = fmaf(w2a[j+1].z, v1.z, za1); za1 = fmaf(w2a[j+1].w, v1.w, za1);
        zb0 = fmaf(w2b[j].x, v0.x, zb0); zb0 = fmaf(w2b[j].y, v0.y, zb0);
        zb0 = fmaf(w2b[j].z, v0.z, zb0); zb0 = fmaf(w2b[j].w, v0.w, zb0);
        zb1 = fmaf(w2b[j+1].x, v1.x, zb1); zb1 = fmaf(w2b[j+1].y, v1.y, zb1);
        zb1 = fmaf(w2b[j+1].z, v1.z, zb1); zb1 = fmaf(w2b[j+1].w, v1.w, zb1);
      }
      ma = fmaxf(ma, za0 + za1); mb = fmaxf(mb, zb0 + zb1);
    }
    float* hp = hT + (size_t)idx * 128;
    hp[lane] = ma; hp[64 + lane] = mb;   // coalesced
    __syncthreads();
  }
}

// ---------------- Kernel 3: 128->1024 + relu + max over N -------------------
__global__ __launch_bounds__(256) void inception_kernel(
    const float* __restrict__ hT, const float* __restrict__ Wi,
    const float* __restrict__ bi, unsigned* __restrict__ g) {
  const int tid = threadIdx.x;
  const int o = blockIdx.y * 256 + tid;
  const int b = blockIdx.z;
  const int n0 = blockIdx.x * 256;
  float4 wreg[32];
  const float4* w4 = (const float4*)(Wi + (size_t)o * 128);
#pragma unroll
  for (int j = 0; j < 32; ++j) wreg[j] = w4[j];
  const float bo = bi[o];
  float gmax = 0.f;                      // relu folded into max
  for (int n = n0; n < n0 + 256; ++n) {
    const float4* h4 = (const float4*)(hT + ((size_t)b * NPTS + n) * 128);
    float a0 = bo, a1 = 0.f, a2 = 0.f, a3 = 0.f;
#pragma unroll
    for (int j = 0; j < 32; j += 4) {
      float4 v0 = h4[j], v1 = h4[j+1], v2 = h4[j+2], v3 = h4[j+3];
      a0 = fmaf(wreg[j].x, v0.x, a0); a0 = fmaf(wreg[j].y, v0.y, a0);
      a0 = fmaf(wreg[j].z, v0.z, a0); a0 = fmaf(wreg[j].w, v0.w, a0);
      a1 = fmaf(wreg[j+1].x, v1.x, a1); a1 = fmaf(wreg[j+1].y, v1.y, a1);
      a1 = fmaf(wreg[j+1].z, v1.z, a1); a1 = fmaf(wreg[j+1].w, v1.w, a1);
      a2 = fmaf(wreg[j+2].x, v2.x, a2); a2 = fmaf(wreg[j+2].y, v2.y, a2);
      a2 = fmaf(wreg[j+2].z, v2.z, a2); a2 = fmaf(wreg[j+2].w, v2.w, a2);
      a3 = fmaf(wreg[j+3].x, v3.x, a3); a3 = fmaf(wreg[j+3].y, v3.y, a3);
      a3 = fmaf(wreg[j+3].z, v3.z, a3); a3 = fmaf(wreg[j+3].w, v3.w, a3);
    }
    gmax = fmaxf(gmax, (a0 + a1) + (a2 + a3));
  }
  atomicMax(&g[b * 1024 + o], __float_as_uint(gmax));  // gmax >= 0: bits monotone
}

// ---------------- Kernel 4: head 1024->512->256->9 + I ----------------------
__global__ __launch_bounds__(512) void head_kernel(
    const unsigned* __restrict__ g, const float* __restrict__ Wg1,
    const float* __restrict__ bg1, const float* __restrict__ Wg2,
    const float* __restrict__ bg2, const float* __restrict__ Wl,
    const float* __restrict__ bl, float* __restrict__ out) {
  __shared__ __align__(16) float gl[1024];
  __shared__ __align__(16) float g1l[512];
  __shared__ __align__(16) float g2l[256];
  const int tid = threadIdx.x;
  const int b = blockIdx.x;
  for (int i = tid; i < 1024; i += 512) gl[i] = __uint_as_float(g[b * 1024 + i]);
  __syncthreads();
  {
    const float4* w = (const float4*)(Wg1 + (size_t)tid * 1024);
    const float4* gv = (const float4*)gl;
    float a0 = bg1[tid], a1 = 0.f, a2 = 0.f, a3 = 0.f;
    for (int j = 0; j < 256; j += 4) {
      float4 w0 = w[j], w1 = w[j+1], w2 = w[j+2], w3 = w[j+3];
      float4 v0 = gv[j], v1 = gv[j+1], v2 = gv[j+2], v3 = gv[j+3];
      a0 = fmaf(w0.x, v0.x, a0); a0 = fmaf(w0.y, v0.y, a0);
      a0 = fmaf(w0.z, v0.z, a0); a0 = fmaf(w0.w, v0.w, a0);
      a1 = fmaf(w1.x, v1.x, a1); a1 = fmaf(w1.y, v1.y, a1);
      a1 = fmaf(w1.z, v1.z, a1); a1 = fmaf(w1.w, v1.w, a1);
      a2 = fmaf(w2.x, v2.x, a2); a2 = fmaf(w2.y, v2.y, a2);
      a2 = fmaf(w2.z, v2.z, a2); a2 = fmaf(w2.w, v2.w, a2);
      a3 = fmaf(w3.x, v3.x, a3); a3 = fmaf(w3.y, v3.y, a3);
      a3 = fmaf(w3.z, v3.z, a3); a3 = fmaf(w3.w, v3.w, a3);
    }
    g1l[tid] = fmaxf((a0 + a1) + (a2 + a3), 0.f);
  }
  __syncthreads();
  if (tid < 256) {
    const float4* w = (const float4*)(Wg2 + (size_t)tid * 512);
    const float4* gv = (const float4*)g1l;
    float a0 = bg2[tid], a1 = 0.f;
    for (int j = 0; j < 128; j += 2) {
      float4 w0 = w[j], w1 = w[j+1];
      float4 v0 = gv[j], v1 = gv[j+1];
      a0 = fmaf(w0.x, v0.x, a0); a0 = fmaf(w0.y, v0.y, a0);
      a0 = fmaf(w0.z, v0.z, a0); a0 = fmaf(w0.w, v0.w, a0);
      a1 = fmaf(w1.x, v1.x, a1); a1 = fmaf(w1.y, v1.y, a1);
      a1 = fmaf(w1.z, v1.z, a1); a1 = fmaf(w1.w, v1.w, a1);
    }
    g2l[tid] = fmaxf(a0 + a1, 0.f);
  }
  __syncthreads();
  if (tid < 9) {
    float acc = bl[tid];
    for (int c = 0; c < 256; ++c) acc = fmaf(Wl[tid * 256 + c], g2l[c], acc);
    if (tid == 0 || tid == 4 || tid == 8) acc += 1.0f;  // + eye(3)
    out[b * 9 + tid] = acc;
  }
}

extern "C" void kernel_launch(void* const* d_in, const int* in_sizes, int n_in,
                              void* d_out, int out_size, void* d_ws, size_t ws_size,
                              hipStream_t stream) {
  const float* x   = (const float*)d_in[0];
  const float* W1  = (const float*)d_in[1];
  const float* b1  = (const float*)d_in[2];
  const float* W2  = (const float*)d_in[3];
  const float* b2  = (const float*)d_in[4];
  const float* Wi  = (const float*)d_in[5];
  const float* bi  = (const float*)d_in[6];
  const float* Wg1 = (const float*)d_in[7];
  const float* bg1 = (const float*)d_in[8];
  const float* Wg2 = (const float*)d_in[9];
  const float* bg2 = (const float*)d_in[10];
  const float* Wl  = (const float*)d_in[11];
  const float* bl  = (const float*)d_in[12];

  int*      knn = (int*)d_ws;                                  // 2.62 MB
  float*    hT  = (float*)((char*)d_ws + (3u << 20));          // 16 MB (B,N,128)
  unsigned* g   = (unsigned*)((char*)d_ws + (19u << 20));      // 32 KB

  knn_kernel<<<8 * NPTS, 256, 0, stream>>>(x, knn);
  edge_kernel<<<8 * NPTS / 8, 64, 0, stream>>>(x, knn, W1, b1, W2, b2, hT);
  hipMemsetAsync(g, 0, 8 * 1024 * sizeof(unsigned), stream);
  inception_kernel<<<dim3(16, 4, 8), 256, 0, stream>>>(hT, Wi, bi, g);
  head_kernel<<<8, 512, 0, stream>>>(g, Wg1, bg1, Wg2, bg2, Wl, bl, (float*)d_out);
}

// Round 2
// 666.196 us; speedup vs baseline: 2.4627x; 2.4627x over previous
//
#include <hip/hip_runtime.h>
#include <stdint.h>

typedef unsigned long long u64;
typedef unsigned short ushort_t;
#define NPTS 4096
#define KNN 20

using bf16x8 = __attribute__((ext_vector_type(8))) short;
using f32x4  = __attribute__((ext_vector_type(4))) float;

__device__ __forceinline__ unsigned orderbits(float f) {
  unsigned u = __float_as_uint(f);
  return ((int)u < 0) ? ~u : (u | 0x80000000u);
}

__device__ __forceinline__ ushort_t f2bf(float f) {  // RNE, finite inputs
  unsigned u = __float_as_uint(f);
  u += 0x7fffu + ((u >> 16) & 1u);
  return (ushort_t)(u >> 16);
}

__device__ __forceinline__ u64 shflxor64(u64 v, int m) {
  unsigned lo = __shfl_xor((unsigned)(v & 0xffffffffull), m, 64);
  unsigned hi = __shfl_xor((unsigned)(v >> 32), m, 64);
  return (((u64)hi) << 32) | lo;
}

// ---------------- Kernel 1: exact KNN via radix-select on (distbits, idx) ----
__global__ __launch_bounds__(256) void knn_kernel(const float* __restrict__ x,
                                                  int* __restrict__ knn_out) {
  __shared__ unsigned keys[NPTS];
  __shared__ unsigned hist[2048];
  __shared__ unsigned wsum[4];
  __shared__ unsigned sBstar, sCnt, sCand;
  __shared__ u64 cand[256];

  const int tid = threadIdx.x;
  const int bid = blockIdx.x;
  const int b = bid >> 12;
  const int n = bid & 4095;
  const float* xb = x + (size_t)b * 3 * NPTS;
  const float xn0 = xb[n], xn1 = xb[NPTS + n], xn2 = xb[2 * NPTS + n];
  const float sqn = __fadd_rn(__fadd_rn(__fmul_rn(xn0, xn0), __fmul_rn(xn1, xn1)),
                              __fmul_rn(xn2, xn2));

  for (int i = tid; i < 2048; i += 256) hist[i] = 0;
  if (tid == 0) { sCnt = 0; sCand = 0; }
  __syncthreads();

  for (int m = tid; m < NPTS; m += 256) {
    float a0 = xb[m], a1 = xb[NPTS + m], a2 = xb[2 * NPTS + m];
    float inner = __fadd_rn(__fadd_rn(__fmul_rn(xn0, a0), __fmul_rn(xn1, a1)),
                            __fmul_rn(xn2, a2));
    float sqm = __fadd_rn(__fadd_rn(__fmul_rn(a0, a0), __fmul_rn(a1, a1)),
                          __fmul_rn(a2, a2));
    float d = __fadd_rn(__fsub_rn(sqn, __fmul_rn(2.0f, inner)), sqm);
    unsigned u = orderbits(d);
    keys[m] = u;
    atomicAdd(&hist[u >> 21], 1u);
  }
  __syncthreads();

  unsigned local = 0;
#pragma unroll
  for (int j = 0; j < 8; ++j) local += hist[tid * 8 + j];
  unsigned incl = local;
  const int lane = tid & 63, wid = tid >> 6;
  for (int off = 1; off < 64; off <<= 1) {
    unsigned v = __shfl_up(incl, off, 64);
    if (lane >= off) incl += v;
  }
  if (lane == 63) wsum[wid] = incl;
  __syncthreads();
  unsigned woff = 0;
  for (int w = 0; w < wid; ++w) woff += wsum[w];
  unsigned excl = woff + incl - local;
  if (excl < KNN && excl + local >= KNN) {
    unsigned cum = excl;
#pragma unroll
    for (int j = 0; j < 8; ++j) {
      unsigned c = hist[tid * 8 + j];
      if (cum + c >= KNN) { sBstar = tid * 8 + j; break; }
      cum += c;
    }
  }
  __syncthreads();

  const unsigned Bstar = sBstar;
  const int base = bid * KNN;
  for (int m = tid; m < NPTS; m += 256) {
    unsigned u = keys[m];
    unsigned bkt = u >> 21;
    if (bkt < Bstar) {
      unsigned p = atomicAdd(&sCnt, 1u);
      knn_out[base + p] = m;
    } else if (bkt == Bstar) {
      unsigned p = atomicAdd(&sCand, 1u);
      if (p < 256) cand[p] = (((u64)u) << 32) | (unsigned)m;
    }
  }
  __syncthreads();
  const int nsel = (int)sCnt;
  const int ncand = min((int)sCand, 256);
  const int ntake = KNN - nsel;
  if (tid < 64) {
    volatile u64* vc = cand;
    for (int t = 0; t < ntake; ++t) {
      u64 mk = ~0ull;
      for (int i = tid; i < ncand; i += 64) { u64 v = vc[i]; if (v < mk) mk = v; }
      for (int off = 32; off; off >>= 1) { u64 o = shflxor64(mk, off); if (o < mk) mk = o; }
      if (tid == 0) knn_out[base + nsel + t] = (int)(unsigned)(mk & 0xffffffffull);
      for (int i = tid; i < ncand; i += 64) { if (vc[i] == mk) vc[i] = ~0ull; }
    }
  }
}

// ---------------- Kernel 2: edge MLP 6->64->128, max over K -----------------
// one wave per point; h stored TRANSPOSED as (B, N, 128) bf16 for MFMA feed
__global__ __launch_bounds__(64) void edge_kernel(
    const float* __restrict__ x, const int* __restrict__ knn,
    const float* __restrict__ W1, const float* __restrict__ b1,
    const float* __restrict__ W2, const float* __restrict__ b2,
    ushort_t* __restrict__ hT) {
  __shared__ __align__(16) float edgeL[KNN * 8];
  __shared__ __align__(16) float h1L[KNN * 64];
  const int lane = threadIdx.x;

  float w1r[6];
#pragma unroll
  for (int j = 0; j < 6; ++j) w1r[j] = W1[lane * 6 + j];
  const float b1r = b1[lane];
  float4 w2a[16], w2b[16];
  const float4* W2a4 = (const float4*)(W2 + (size_t)lane * 64);
  const float4* W2b4 = (const float4*)(W2 + (size_t)(lane + 64) * 64);
#pragma unroll
  for (int j = 0; j < 16; ++j) { w2a[j] = W2a4[j]; w2b[j] = W2b4[j]; }
  const float b2a = b2[lane], b2bv = b2[lane + 64];

  for (int it = 0; it < 8; ++it) {
    const int idx = blockIdx.x * 8 + it;
    const int b = idx >> 12, n = idx & 4095;
    const float* xb = x + (size_t)b * 3 * NPTS;
    const float c0 = xb[n], c1 = xb[NPTS + n], c2 = xb[2 * NPTS + n];
    if (lane < KNN) {
      int nb = knn[idx * KNN + lane];
      float a0 = xb[nb], a1 = xb[NPTS + nb], a2 = xb[2 * NPTS + nb];
      float* e = &edgeL[lane * 8];
      e[0] = c0; e[1] = c1; e[2] = c2;
      e[3] = a0 - c0; e[4] = a1 - c1; e[5] = a2 - c2;
    }
    __syncthreads();
#pragma unroll
    for (int k = 0; k < KNN; ++k) {
      const float* e = &edgeL[k * 8];
      float acc = b1r;
      acc = fmaf(w1r[0], e[0], acc); acc = fmaf(w1r[1], e[1], acc);
      acc = fmaf(w1r[2], e[2], acc); acc = fmaf(w1r[3], e[3], acc);
      acc = fmaf(w1r[4], e[4], acc); acc = fmaf(w1r[5], e[5], acc);
      h1L[k * 64 + lane] = fmaxf(acc, 0.f);
    }
    __syncthreads();
    float ma = 0.f, mb = 0.f;
    for (int k = 0; k < KNN; ++k) {
      const float4* h4 = (const float4*)&h1L[k * 64];
      float za0 = b2a, za1 = 0.f, zb0 = b2bv, zb1 = 0.f;
#pragma unroll
      for (int j = 0; j < 16; j += 2) {
        float4 v0 = h4[j], v1 = h4[j + 1];
        za0 = fmaf(w2a[j].x, v0.x, za0); za0 = fmaf(w2a[j].y, v0.y, za0);
        za0 = fmaf(w2a[j].z, v0.z, za0); za0 = fmaf(w2a[j].w, v0.w, za0);
        za1 = fmaf(w2a[j+1].x, v1.x, za1); za1 = fmaf(w2a[j+1].y, v1.y, za1);
        za1 = fmaf(w2a[j+1].z, v1.z, za1); za1 = fmaf(w2a[j+1].w, v1.w, za1);
        zb0 = fmaf(w2b[j].x, v0.x, zb0); zb0 = fmaf(w2b[j].y, v0.y, zb0);
        zb0 = fmaf(w2b[j].z, v0.z, zb0); zb0 = fmaf(w2b[j].w, v0.w, zb0);
        zb1 = fmaf(w2b[j+1].x, v1.x, zb1); zb1 = fmaf(w2b[j+1].y, v1.y, zb1);
        zb1 = fmaf(w2b[j+1].z, v1.z, zb1); zb1 = fmaf(w2b[j+1].w, v1.w, zb1);
      }
      ma = fmaxf(ma, za0 + za1); mb = fmaxf(mb, zb0 + zb1);
    }
    ushort_t* hp = hT + (size_t)idx * 128;
    hp[lane] = f2bf(ma); hp[64 + lane] = f2bf(mb);
    __syncthreads();
  }
}

// ---------------- Kernel 2.5: Wi fp32 -> bf16 -------------------------------
__global__ __launch_bounds__(256) void convert_wi(const float* __restrict__ Wi,
                                                  ushort_t* __restrict__ wiB) {
  int i = blockIdx.x * 256 + threadIdx.x;  // 131072 total
  wiB[i] = f2bf(Wi[i]);
}

// ---------------- Kernel 3: 128->1024 via bf16 MFMA + relu + max over N -----
// block: 256 thr = 4 waves in 2x2; tile M=128 points x N=128 outputs, K=128.
// LDS rows padded to 136 bf16 (272 B = 68 dwords) to break bank conflicts.
#define LDP 136
__global__ __launch_bounds__(256, 2) void inception_mfma(
    const ushort_t* __restrict__ hT, const ushort_t* __restrict__ wiB,
    const float* __restrict__ bi, unsigned* __restrict__ g) {
  __shared__ __align__(16) ushort_t hS[128 * LDP];
  __shared__ __align__(16) ushort_t wS[128 * LDP];
  const int tid = threadIdx.x;
  const int b = blockIdx.z;
  const int m0 = blockIdx.x * 128;   // point tile
  const int n0 = blockIdx.y * 128;   // output tile

  const ushort_t* hg = hT + ((size_t)b * NPTS + m0) * 128;
  const ushort_t* wg = wiB + (size_t)n0 * 128;
#pragma unroll
  for (int i = 0; i < 8; ++i) {      // 2048 chunks of 16 B each, 256 thr
    int chunk = i * 256 + tid;
    int row = chunk >> 4, c = chunk & 15;
    *(int4*)&hS[row * LDP + c * 8] = *(const int4*)&hg[row * 128 + c * 8];
    *(int4*)&wS[row * LDP + c * 8] = *(const int4*)&wg[row * 128 + c * 8];
  }
  __syncthreads();

  const int lane = tid & 63, wid = tid >> 6;
  const int ln = lane & 15, quad = lane >> 4;
  const int mw = (wid >> 1) * 64, nw = (wid & 1) * 64;

  f32x4 acc[4][4];
#pragma unroll
  for (int mi = 0; mi < 4; ++mi)
#pragma unroll
    for (int ni = 0; ni < 4; ++ni) acc[mi][ni] = (f32x4){0.f, 0.f, 0.f, 0.f};

#pragma unroll
  for (int kk = 0; kk < 4; ++kk) {   // K = 4 x 32
    bf16x8 af[4], bfr[4];
    const int ko = kk * 32 + quad * 8;
#pragma unroll
    for (int mi = 0; mi < 4; ++mi)
      af[mi] = *(const bf16x8*)&hS[(mw + mi * 16 + ln) * LDP + ko];
#pragma unroll
    for (int ni = 0; ni < 4; ++ni)
      bfr[ni] = *(const bf16x8*)&wS[(nw + ni * 16 + ln) * LDP + ko];
#pragma unroll
    for (int mi = 0; mi < 4; ++mi)
#pragma unroll
      for (int ni = 0; ni < 4; ++ni)
        acc[mi][ni] = __builtin_amdgcn_mfma_f32_16x16x32_bf16(
            af[mi], bfr[ni], acc[mi][ni], 0, 0, 0);
  }

  // max over the 64 M-rows this wave owns; C layout: col=lane&15, row=quad*4+reg
#pragma unroll
  for (int ni = 0; ni < 4; ++ni) {
    float v = acc[0][ni][0];
#pragma unroll
    for (int mi = 0; mi < 4; ++mi)
#pragma unroll
      for (int r = 0; r < 4; ++r) v = fmaxf(v, acc[mi][ni][r]);
    v = fmaxf(v, __shfl_xor(v, 16, 64));
    v = fmaxf(v, __shfl_xor(v, 32, 64));
    if (quad == 0) {
      int o = n0 + nw + ni * 16 + ln;
      float val = fmaxf(v + bi[o], 0.f);   // bias+relu after max: monotone
      atomicMax(&g[b * 1024 + o], __float_as_uint(val));
    }
  }
}

// ---------------- Kernel 4: head 1024->512->256->9 + I ----------------------
__global__ __launch_bounds__(512) void head_kernel(
    const unsigned* __restrict__ g, const float* __restrict__ Wg1,
    const float* __restrict__ bg1, const float* __restrict__ Wg2,
    const float* __restrict__ bg2, const float* __restrict__ Wl,
    const float* __restrict__ bl, float* __restrict__ out) {
  __shared__ __align__(16) float gl[1024];
  __shared__ __align__(16) float g1l[512];
  __shared__ __align__(16) float g2l[256];
  const int tid = threadIdx.x;
  const int b = blockIdx.x;
  for (int i = tid; i < 1024; i += 512) gl[i] = __uint_as_float(g[b * 1024 + i]);
  __syncthreads();
  {
    const float4* w = (const float4*)(Wg1 + (size_t)tid * 1024);
    const float4* gv = (const float4*)gl;
    float a0 = bg1[tid], a1 = 0.f, a2 = 0.f, a3 = 0.f;
    for (int j = 0; j < 256; j += 4) {
      float4 w0 = w[j], w1 = w[j+1], w2 = w[j+2], w3 = w[j+3];
      float4 v0 = gv[j], v1 = gv[j+1], v2 = gv[j+2], v3 = gv[j+3];
      a0 = fmaf(w0.x, v0.x, a0); a0 = fmaf(w0.y, v0.y, a0);
      a0 = fmaf(w0.z, v0.z, a0); a0 = fmaf(w0.w, v0.w, a0);
      a1 = fmaf(w1.x, v1.x, a1); a1 = fmaf(w1.y, v1.y, a1);
      a1 = fmaf(w1.z, v1.z, a1); a1 = fmaf(w1.w, v1.w, a1);
      a2 = fmaf(w2.x, v2.x, a2); a2 = fmaf(w2.y, v2.y, a2);
      a2 = fmaf(w2.z, v2.z, a2); a2 = fmaf(w2.w, v2.w, a2);
      a3 = fmaf(w3.x, v3.x, a3); a3 = fmaf(w3.y, v3.y, a3);
      a3 = fmaf(w3.z, v3.z, a3); a3 = fmaf(w3.w, v3.w, a3);
    }
    g1l[tid] = fmaxf((a0 + a1) + (a2 + a3), 0.f);
  }
  __syncthreads();
  if (tid < 256) {
    const float4* w = (const float4*)(Wg2 + (size_t)tid * 512);
    const float4* gv = (const float4*)g1l;
    float a0 = bg2[tid], a1 = 0.f;
    for (int j = 0; j < 128; j += 2) {
      float4 w0 = w[j], w1 = w[j+1];
      float4 v0 = gv[j], v1 = gv[j+1];
      a0 = fmaf(w0.x, v0.x, a0); a0 = fmaf(w0.y, v0.y, a0);
      a0 = fmaf(w0.z, v0.z, a0); a0 = fmaf(w0.w, v0.w, a0);
      a1 = fmaf(w1.x, v1.x, a1); a1 = fmaf(w1.y, v1.y, a1);
      a1 = fmaf(w1.z, v1.z, a1); a1 = fmaf(w1.w, v1.w, a1);
    }
    g2l[tid] = fmaxf(a0 + a1, 0.f);
  }
  __syncthreads();
  if (tid < 9) {
    float acc = bl[tid];
    for (int c = 0; c < 256; ++c) acc = fmaf(Wl[tid * 256 + c], g2l[c], acc);
    if (tid == 0 || tid == 4 || tid == 8) acc += 1.0f;
    out[b * 9 + tid] = acc;
  }
}

extern "C" void kernel_launch(void* const* d_in, const int* in_sizes, int n_in,
                              void* d_out, int out_size, void* d_ws, size_t ws_size,
                              hipStream_t stream) {
  const float* x   = (const float*)d_in[0];
  const float* W1  = (const float*)d_in[1];
  const float* b1  = (const float*)d_in[2];
  const float* W2  = (const float*)d_in[3];
  const float* b2  = (const float*)d_in[4];
  const float* Wi  = (const float*)d_in[5];
  const float* bi  = (const float*)d_in[6];
  const float* Wg1 = (const float*)d_in[7];
  const float* bg1 = (const float*)d_in[8];
  const float* Wg2 = (const float*)d_in[9];
  const float* bg2 = (const float*)d_in[10];
  const float* Wl  = (const float*)d_in[11];
  const float* bl  = (const float*)d_in[12];

  int*       knn = (int*)d_ws;                                   // 2.62 MB @ 0
  ushort_t*  hT  = (ushort_t*)((char*)d_ws + (3u << 20));        // 8 MB bf16 (B,N,128)
  ushort_t*  wiB = (ushort_t*)((char*)d_ws + (12u << 20));       // 256 KB bf16
  unsigned*  g   = (unsigned*)((char*)d_ws + (13u << 20));       // 32 KB

  knn_kernel<<<8 * NPTS, 256, 0, stream>>>(x, knn);
  edge_kernel<<<8 * NPTS / 8, 64, 0, stream>>>(x, knn, W1, b1, W2, b2, hT);
  convert_wi<<<512, 256, 0, stream>>>(Wi, wiB);
  hipMemsetAsync(g, 0, 8 * 1024 * sizeof(unsigned), stream);
  inception_mfma<<<dim3(32, 8, 8), 256, 0, stream>>>(hT, wiB, bi, g);
  head_kernel<<<8, 512, 0, stream>>>(g, Wg1, bg1, Wg2, bg2, Wl, bl, (float*)d_out);
}

// Round 3
// 505.058 us; speedup vs baseline: 3.2484x; 1.3190x over previous
//
#include <hip/hip_runtime.h>
#include <stdint.h>

typedef unsigned long long u64;
typedef unsigned short ushort_t;
#define NPTS 4096
#define KNN 20

using bf16x8 = __attribute__((ext_vector_type(8))) short;
using f32x4  = __attribute__((ext_vector_type(4))) float;

__device__ __forceinline__ unsigned orderbits(float f) {
  unsigned u = __float_as_uint(f);
  return ((int)u < 0) ? ~u : (u | 0x80000000u);
}

__device__ __forceinline__ ushort_t f2bf(float f) {  // RNE, finite inputs
  unsigned u = __float_as_uint(f);
  u += 0x7fffu + ((u >> 16) & 1u);
  return (ushort_t)(u >> 16);
}

__device__ __forceinline__ u64 shflxor64(u64 v, int m) {
  unsigned lo = __shfl_xor((unsigned)(v & 0xffffffffull), m, 64);
  unsigned hi = __shfl_xor((unsigned)(v >> 32), m, 64);
  return (((u64)hi) << 32) | lo;
}

// ---------------- Kernel 1: exact KNN via radix-select on (distbits, idx) ----
__global__ __launch_bounds__(256) void knn_kernel(const float* __restrict__ x,
                                                  int* __restrict__ knn_out) {
  __shared__ unsigned keys[NPTS];
  __shared__ unsigned hist[2048];
  __shared__ unsigned wsum[4];
  __shared__ unsigned sBstar, sCnt, sCand;
  __shared__ u64 cand[256];

  const int tid = threadIdx.x;
  const int bid = blockIdx.x;
  const int b = bid >> 12;
  const int n = bid & 4095;
  const float* xb = x + (size_t)b * 3 * NPTS;
  const float xn0 = xb[n], xn1 = xb[NPTS + n], xn2 = xb[2 * NPTS + n];
  const float sqn = __fadd_rn(__fadd_rn(__fmul_rn(xn0, xn0), __fmul_rn(xn1, xn1)),
                              __fmul_rn(xn2, xn2));

  for (int i = tid; i < 2048; i += 256) hist[i] = 0;
  if (tid == 0) { sCnt = 0; sCand = 0; }
  __syncthreads();

  for (int m = tid; m < NPTS; m += 256) {
    float a0 = xb[m], a1 = xb[NPTS + m], a2 = xb[2 * NPTS + m];
    float inner = __fadd_rn(__fadd_rn(__fmul_rn(xn0, a0), __fmul_rn(xn1, a1)),
                            __fmul_rn(xn2, a2));
    float sqm = __fadd_rn(__fadd_rn(__fmul_rn(a0, a0), __fmul_rn(a1, a1)),
                          __fmul_rn(a2, a2));
    float d = __fadd_rn(__fsub_rn(sqn, __fmul_rn(2.0f, inner)), sqm);
    unsigned u = orderbits(d);
    keys[m] = u;
    atomicAdd(&hist[u >> 21], 1u);
  }
  __syncthreads();

  unsigned local = 0;
#pragma unroll
  for (int j = 0; j < 8; ++j) local += hist[tid * 8 + j];
  unsigned incl = local;
  const int lane = tid & 63, wid = tid >> 6;
  for (int off = 1; off < 64; off <<= 1) {
    unsigned v = __shfl_up(incl, off, 64);
    if (lane >= off) incl += v;
  }
  if (lane == 63) wsum[wid] = incl;
  __syncthreads();
  unsigned woff = 0;
  for (int w = 0; w < wid; ++w) woff += wsum[w];
  unsigned excl = woff + incl - local;
  if (excl < KNN && excl + local >= KNN) {
    unsigned cum = excl;
#pragma unroll
    for (int j = 0; j < 8; ++j) {
      unsigned c = hist[tid * 8 + j];
      if (cum + c >= KNN) { sBstar = tid * 8 + j; break; }
      cum += c;
    }
  }
  __syncthreads();

  const unsigned Bstar = sBstar;
  const int base = bid * KNN;
  for (int m = tid; m < NPTS; m += 256) {
    unsigned u = keys[m];
    unsigned bkt = u >> 21;
    if (bkt < Bstar) {
      unsigned p = atomicAdd(&sCnt, 1u);
      knn_out[base + p] = m;
    } else if (bkt == Bstar) {
      unsigned p = atomicAdd(&sCand, 1u);
      if (p < 256) cand[p] = (((u64)u) << 32) | (unsigned)m;
    }
  }
  __syncthreads();
  const int nsel = (int)sCnt;
  const int ncand = min((int)sCand, 256);
  const int ntake = KNN - nsel;
  if (tid < 64) {
    volatile u64* vc = cand;
    for (int t = 0; t < ntake; ++t) {
      u64 mk = ~0ull;
      for (int i = tid; i < ncand; i += 64) { u64 v = vc[i]; if (v < mk) mk = v; }
      for (int off = 32; off; off >>= 1) { u64 o = shflxor64(mk, off); if (o < mk) mk = o; }
      if (tid == 0) knn_out[base + nsel + t] = (int)(unsigned)(mk & 0xffffffffull);
      for (int i = tid; i < ncand; i += 64) { if (vc[i] == mk) vc[i] = ~0ull; }
    }
  }
}

// ---------------- Kernel 2: fused edge MLP 6->64->128 (MFMA) + max over K ---
// 256 thr = 4 waves; 8 points/block. Stage 1: 32-thread group per point
// computes h1 (20x64, relu) scalar into LDS bf16. Stage 2: per wave, 2 points:
// h1(32x64) x W2^T(64x128) via 16x16x32 bf16 MFMA, W2 entirely in registers.
// LDS chunk-XOR swizzle (c ^= row&7) keeps writes and b128 A-reads conflict-free.
__global__ __launch_bounds__(256, 2) void edge_fused(
    const float* __restrict__ x, const int* __restrict__ knn,
    const float* __restrict__ W1, const float* __restrict__ b1,
    const float* __restrict__ W2, const float* __restrict__ b2,
    ushort_t* __restrict__ hT) {
  __shared__ __align__(16) ushort_t h1S[8 * 32 * 64];  // 32 KB
  const int tid = threadIdx.x;
  const int lane = tid & 63, wv = tid >> 6;
  const int ln = lane & 15, quad = lane >> 4;

  // ---- W2 -> 16 bf16 B-fragments in registers (n-tile 0..7, k-step 0..1)
  bf16x8 Bf[8][2];
#pragma unroll
  for (int n = 0; n < 8; ++n)
#pragma unroll
    for (int s = 0; s < 2; ++s) {
      const float* wp = W2 + (size_t)(n * 16 + ln) * 64 + s * 32 + quad * 8;
      float4 f0 = *(const float4*)wp;
      float4 f1 = *(const float4*)(wp + 4);
      bf16x8 t;
      t[0] = (short)f2bf(f0.x); t[1] = (short)f2bf(f0.y);
      t[2] = (short)f2bf(f0.z); t[3] = (short)f2bf(f0.w);
      t[4] = (short)f2bf(f1.x); t[5] = (short)f2bf(f1.y);
      t[6] = (short)f2bf(f1.z); t[7] = (short)f2bf(f1.w);
      Bf[n][s] = t;
    }
  float b2r[8];
#pragma unroll
  for (int n = 0; n < 8; ++n) b2r[n] = b2[n * 16 + ln];  // used by quad==0 only

  // ---- stage 1: h1 = relu(W1 @ edge + b1), 2 channels/thread, 20 edges
  {
    const int p = tid >> 5, s5 = tid & 31;
    const int idx = blockIdx.x * 8 + p;
    const int b = idx >> 12, n = idx & 4095;
    const float* xb = x + (size_t)b * 3 * NPTS;
    const float cx = xb[n], cy = xb[NPTS + n], cz = xb[2 * NPTS + n];
    const int c0 = 2 * s5;
    float w1a[6], w1b[6];
#pragma unroll
    for (int j = 0; j < 6; ++j) {
      w1a[j] = W1[c0 * 6 + j];
      w1b[j] = W1[(c0 + 1) * 6 + j];
    }
    const float b1a = b1[c0], b1b = b1[c0 + 1];
    const int kbase = idx * KNN;
    unsigned* h1d = (unsigned*)h1S;
#pragma unroll 4
    for (int k = 0; k < KNN; ++k) {
      int nb = knn[kbase + k];
      float ax = xb[nb], ay = xb[NPTS + nb], az = xb[2 * NPTS + nb];
      float e3 = ax - cx, e4 = ay - cy, e5 = az - cz;
      float za = b1a, zb = b1b;
      za = fmaf(w1a[0], cx, za); zb = fmaf(w1b[0], cx, zb);
      za = fmaf(w1a[1], cy, za); zb = fmaf(w1b[1], cy, zb);
      za = fmaf(w1a[2], cz, za); zb = fmaf(w1b[2], cz, zb);
      za = fmaf(w1a[3], e3, za); zb = fmaf(w1b[3], e3, zb);
      za = fmaf(w1a[4], e4, za); zb = fmaf(w1b[4], e4, zb);
      za = fmaf(w1a[5], e5, za); zb = fmaf(w1b[5], e5, zb);
      unsigned pk = (unsigned)f2bf(fmaxf(za, 0.f)) |
                    ((unsigned)f2bf(fmaxf(zb, 0.f)) << 16);
      int row = p * 32 + k;
      int dw = row * 32 + (((s5 >> 2) ^ (row & 7)) << 2) + (s5 & 3);
      h1d[dw] = pk;
    }
  }
  __syncthreads();

  // ---- stage 2: per wave, points {2w, 2w+1}; rows 20..31 are garbage -> mask
  const int base_idx = blockIdx.x * 8;
#pragma unroll
  for (int pi = 0; pi < 2; ++pi) {
    const int ps = wv * 2 + pi;
    const int sw = ln & 7;
    float vmax[8];
    {  // tile 0: edge rows 0..15 (all real)
      const int row = ps * 32 + ln;
      bf16x8 A0 = *(const bf16x8*)&h1S[row * 64 + (((0 + quad) ^ sw) << 3)];
      bf16x8 A1 = *(const bf16x8*)&h1S[row * 64 + (((4 + quad) ^ sw) << 3)];
      f32x4 acc;
#pragma unroll
      for (int n = 0; n < 8; ++n) {
        acc = (f32x4){0.f, 0.f, 0.f, 0.f};
        acc = __builtin_amdgcn_mfma_f32_16x16x32_bf16(A0, Bf[n][0], acc, 0, 0, 0);
        acc = __builtin_amdgcn_mfma_f32_16x16x32_bf16(A1, Bf[n][1], acc, 0, 0, 0);
        vmax[n] = fmaxf(fmaxf(acc[0], acc[1]), fmaxf(acc[2], acc[3]));
      }
    }
    {  // tile 1: edge rows 16..31; real only 16..19 => quad==0
      const int row = ps * 32 + 16 + ln;
      bf16x8 A0 = *(const bf16x8*)&h1S[row * 64 + (((0 + quad) ^ sw) << 3)];
      bf16x8 A1 = *(const bf16x8*)&h1S[row * 64 + (((4 + quad) ^ sw) << 3)];
      f32x4 acc;
#pragma unroll
      for (int n = 0; n < 8; ++n) {
        acc = (f32x4){0.f, 0.f, 0.f, 0.f};
        acc = __builtin_amdgcn_mfma_f32_16x16x32_bf16(A0, Bf[n][0], acc, 0, 0, 0);
        acc = __builtin_amdgcn_mfma_f32_16x16x32_bf16(A1, Bf[n][1], acc, 0, 0, 0);
        float v1 = (quad == 0)
                       ? fmaxf(fmaxf(acc[0], acc[1]), fmaxf(acc[2], acc[3]))
                       : -INFINITY;
        vmax[n] = fmaxf(vmax[n], v1);
      }
    }
    const int gidx = base_idx + ps;
#pragma unroll
    for (int n = 0; n < 8; ++n) {
      float v = vmax[n];
      v = fmaxf(v, __shfl_xor(v, 16, 64));
      v = fmaxf(v, __shfl_xor(v, 32, 64));
      if (quad == 0) {
        hT[(size_t)gidx * 128 + n * 16 + ln] = f2bf(fmaxf(v + b2r[n], 0.f));
      }
    }
  }
}

// ---------------- Kernel 2.5: Wi fp32 -> bf16 -------------------------------
__global__ __launch_bounds__(256) void convert_wi(const float* __restrict__ Wi,
                                                  ushort_t* __restrict__ wiB) {
  int i = blockIdx.x * 256 + threadIdx.x;  // 131072 total
  wiB[i] = f2bf(Wi[i]);
}

// ---------------- Kernel 3: 128->1024 via bf16 MFMA + relu + max over N -----
#define LDP 136
__global__ __launch_bounds__(256, 2) void inception_mfma(
    const ushort_t* __restrict__ hT, const ushort_t* __restrict__ wiB,
    const float* __restrict__ bi, unsigned* __restrict__ g) {
  __shared__ __align__(16) ushort_t hS[128 * LDP];
  __shared__ __align__(16) ushort_t wS[128 * LDP];
  const int tid = threadIdx.x;
  const int b = blockIdx.z;
  const int m0 = blockIdx.x * 128;
  const int n0 = blockIdx.y * 128;

  const ushort_t* hg = hT + ((size_t)b * NPTS + m0) * 128;
  const ushort_t* wg = wiB + (size_t)n0 * 128;
#pragma unroll
  for (int i = 0; i < 8; ++i) {
    int chunk = i * 256 + tid;
    int row = chunk >> 4, c = chunk & 15;
    *(int4*)&hS[row * LDP + c * 8] = *(const int4*)&hg[row * 128 + c * 8];
    *(int4*)&wS[row * LDP + c * 8] = *(const int4*)&wg[row * 128 + c * 8];
  }
  __syncthreads();

  const int lane = tid & 63, wid = tid >> 6;
  const int ln = lane & 15, quad = lane >> 4;
  const int mw = (wid >> 1) * 64, nw = (wid & 1) * 64;

  f32x4 acc[4][4];
#pragma unroll
  for (int mi = 0; mi < 4; ++mi)
#pragma unroll
    for (int ni = 0; ni < 4; ++ni) acc[mi][ni] = (f32x4){0.f, 0.f, 0.f, 0.f};

#pragma unroll
  for (int kk = 0; kk < 4; ++kk) {
    bf16x8 af[4], bfr[4];
    const int ko = kk * 32 + quad * 8;
#pragma unroll
    for (int mi = 0; mi < 4; ++mi)
      af[mi] = *(const bf16x8*)&hS[(mw + mi * 16 + ln) * LDP + ko];
#pragma unroll
    for (int ni = 0; ni < 4; ++ni)
      bfr[ni] = *(const bf16x8*)&wS[(nw + ni * 16 + ln) * LDP + ko];
#pragma unroll
    for (int mi = 0; mi < 4; ++mi)
#pragma unroll
      for (int ni = 0; ni < 4; ++ni)
        acc[mi][ni] = __builtin_amdgcn_mfma_f32_16x16x32_bf16(
            af[mi], bfr[ni], acc[mi][ni], 0, 0, 0);
  }

#pragma unroll
  for (int ni = 0; ni < 4; ++ni) {
    float v = acc[0][ni][0];
#pragma unroll
    for (int mi = 0; mi < 4; ++mi)
#pragma unroll
      for (int r = 0; r < 4; ++r) v = fmaxf(v, acc[mi][ni][r]);
    v = fmaxf(v, __shfl_xor(v, 16, 64));
    v = fmaxf(v, __shfl_xor(v, 32, 64));
    if (quad == 0) {
      int o = n0 + nw + ni * 16 + ln;
      float val = fmaxf(v + bi[o], 0.f);
      atomicMax(&g[b * 1024 + o], __float_as_uint(val));
    }
  }
}

// ---------------- Kernel 4: head 1024->512->256->9 + I ----------------------
__global__ __launch_bounds__(512) void head_kernel(
    const unsigned* __restrict__ g, const float* __restrict__ Wg1,
    const float* __restrict__ bg1, const float* __restrict__ Wg2,
    const float* __restrict__ bg2, const float* __restrict__ Wl,
    const float* __restrict__ bl, float* __restrict__ out) {
  __shared__ __align__(16) float gl[1024];
  __shared__ __align__(16) float g1l[512];
  __shared__ __align__(16) float g2l[256];
  const int tid = threadIdx.x;
  const int b = blockIdx.x;
  for (int i = tid; i < 1024; i += 512) gl[i] = __uint_as_float(g[b * 1024 + i]);
  __syncthreads();
  {
    const float4* w = (const float4*)(Wg1 + (size_t)tid * 1024);
    const float4* gv = (const float4*)gl;
    float a0 = bg1[tid], a1 = 0.f, a2 = 0.f, a3 = 0.f;
    for (int j = 0; j < 256; j += 4) {
      float4 w0 = w[j], w1 = w[j+1], w2 = w[j+2], w3 = w[j+3];
      float4 v0 = gv[j], v1 = gv[j+1], v2 = gv[j+2], v3 = gv[j+3];
      a0 = fmaf(w0.x, v0.x, a0); a0 = fmaf(w0.y, v0.y, a0);
      a0 = fmaf(w0.z, v0.z, a0); a0 = fmaf(w0.w, v0.w, a0);
      a1 = fmaf(w1.x, v1.x, a1); a1 = fmaf(w1.y, v1.y, a1);
      a1 = fmaf(w1.z, v1.z, a1); a1 = fmaf(w1.w, v1.w, a1);
      a2 = fmaf(w2.x, v2.x, a2); a2 = fmaf(w2.y, v2.y, a2);
      a2 = fmaf(w2.z, v2.z, a2); a2 = fmaf(w2.w, v2.w, a2);
      a3 = fmaf(w3.x, v3.x, a3); a3 = fmaf(w3.y, v3.y, a3);
      a3 = fmaf(w3.w, v3.w, a3); a3 = fmaf(w3.z, v3.z, a3);
    }
    g1l[tid] = fmaxf((a0 + a1) + (a2 + a3), 0.f);
  }
  __syncthreads();
  if (tid < 256) {
    const float4* w = (const float4*)(Wg2 + (size_t)tid * 512);
    const float4* gv = (const float4*)g1l;
    float a0 = bg2[tid], a1 = 0.f;
    for (int j = 0; j < 128; j += 2) {
      float4 w0 = w[j], w1 = w[j+1];
      float4 v0 = gv[j], v1 = gv[j+1];
      a0 = fmaf(w0.x, v0.x, a0); a0 = fmaf(w0.y, v0.y, a0);
      a0 = fmaf(w0.z, v0.z, a0); a0 = fmaf(w0.w, v0.w, a0);
      a1 = fmaf(w1.x, v1.x, a1); a1 = fmaf(w1.y, v1.y, a1);
      a1 = fmaf(w1.z, v1.z, a1); a1 = fmaf(w1.w, v1.w, a1);
    }
    g2l[tid] = fmaxf(a0 + a1, 0.f);
  }
  __syncthreads();
  if (tid < 9) {
    float acc = bl[tid];
    for (int c = 0; c < 256; ++c) acc = fmaf(Wl[tid * 256 + c], g2l[c], acc);
    if (tid == 0 || tid == 4 || tid == 8) acc += 1.0f;
    out[b * 9 + tid] = acc;
  }
}

extern "C" void kernel_launch(void* const* d_in, const int* in_sizes, int n_in,
                              void* d_out, int out_size, void* d_ws, size_t ws_size,
                              hipStream_t stream) {
  const float* x   = (const float*)d_in[0];
  const float* W1  = (const float*)d_in[1];
  const float* b1  = (const float*)d_in[2];
  const float* W2  = (const float*)d_in[3];
  const float* b2  = (const float*)d_in[4];
  const float* Wi  = (const float*)d_in[5];
  const float* bi  = (const float*)d_in[6];
  const float* Wg1 = (const float*)d_in[7];
  const float* bg1 = (const float*)d_in[8];
  const float* Wg2 = (const float*)d_in[9];
  const float* bg2 = (const float*)d_in[10];
  const float* Wl  = (const float*)d_in[11];
  const float* bl  = (const float*)d_in[12];

  int*       knn = (int*)d_ws;                                   // 2.62 MB @ 0
  ushort_t*  hT  = (ushort_t*)((char*)d_ws + (3u << 20));        // 8 MB bf16
  ushort_t*  wiB = (ushort_t*)((char*)d_ws + (12u << 20));       // 256 KB bf16
  unsigned*  g   = (unsigned*)((char*)d_ws + (13u << 20));       // 32 KB

  knn_kernel<<<8 * NPTS, 256, 0, stream>>>(x, knn);
  edge_fused<<<8 * NPTS / 8, 256, 0, stream>>>(x, knn, W1, b1, W2, b2, hT);
  convert_wi<<<512, 256, 0, stream>>>(Wi, wiB);
  hipMemsetAsync(g, 0, 8 * 1024 * sizeof(unsigned), stream);
  inception_mfma<<<dim3(32, 8, 8), 256, 0, stream>>>(hT, wiB, bi, g);
  head_kernel<<<8, 512, 0, stream>>>(g, Wg1, bg1, Wg2, bg2, Wl, bl, (float*)d_out);
}

// Round 4
// 356.381 us; speedup vs baseline: 4.6035x; 1.4172x over previous
//
#include <hip/hip_runtime.h>
#include <stdint.h>

typedef unsigned long long u64;
typedef unsigned short ushort_t;
#define NPTS 4096
#define KNN 20

using bf16x8 = __attribute__((ext_vector_type(8))) short;
using f32x4  = __attribute__((ext_vector_type(4))) float;

__device__ __forceinline__ unsigned orderbits(float f) {
  unsigned u = __float_as_uint(f);
  return ((int)u < 0) ? ~u : (u | 0x80000000u);
}

__device__ __forceinline__ ushort_t f2bf(float f) {  // RNE, finite inputs
  unsigned u = __float_as_uint(f);
  u += 0x7fffu + ((u >> 16) & 1u);
  return (ushort_t)(u >> 16);
}

__device__ __forceinline__ u64 shflxor64(u64 v, int m) {
  unsigned lo = __shfl_xor((unsigned)(v & 0xffffffffull), m, 64);
  unsigned hi = __shfl_xor((unsigned)(v >> 32), m, 64);
  return (((u64)hi) << 32) | lo;
}

// ---------------- Kernel 0: sq[b][m] = sum_c x^2 (exact ref association) ----
__global__ __launch_bounds__(256) void sq_kernel(const float* __restrict__ x,
                                                 float* __restrict__ sqg) {
  int i = blockIdx.x * 256 + threadIdx.x;  // 32768
  int b = i >> 12, m = i & 4095;
  const float* xb = x + (size_t)b * 3 * NPTS;
  float a0 = xb[m], a1 = xb[NPTS + m], a2 = xb[2 * NPTS + m];
  sqg[i] = __fadd_rn(__fadd_rn(__fmul_rn(a0, a0), __fmul_rn(a1, a1)),
                     __fmul_rn(a2, a2));
}

// ---------------- Kernel 1: exact KNN, linear-bucket radix select -----------
// 4 points/block; bucket = min(1023, int(max(d,0)*64)) is monotone in d, so
// radix-select is exact; boundary ties resolved on full (orderbits,idx) u64.
#define NB 1024
#define PPB 4
#define CCAP 256
__global__ __launch_bounds__(256) void knn_kernel(const float* __restrict__ x,
                                                  const float* __restrict__ sqg,
                                                  int* __restrict__ knn_out) {
  __shared__ unsigned hist[PPB * NB];   // 16 KB
  __shared__ u64 cand[PPB * CCAP];      // 8 KB
  __shared__ unsigned sB[PPB], sCnt[PPB], sCand[PPB];

  const int tid = threadIdx.x;
  const int bid = blockIdx.x;           // 8192
  const int b = bid >> 10;
  const int n0 = (bid & 1023) * PPB;
  const float* xb = x + (size_t)b * 3 * NPTS;
  const float* sqb = sqg + b * NPTS;

  float qx[PPB], qy[PPB], qz[PPB], qs[PPB];
#pragma unroll
  for (int p = 0; p < PPB; ++p) {
    qx[p] = xb[n0 + p]; qy[p] = xb[NPTS + n0 + p]; qz[p] = xb[2 * NPTS + n0 + p];
    qs[p] = sqb[n0 + p];
  }
  for (int i = tid; i < PPB * NB; i += 256) hist[i] = 0;
  if (tid < PPB) { sCnt[tid] = 0; sCand[tid] = 0; }
  __syncthreads();

  // pass 1: histogram
  for (int m = tid; m < NPTS; m += 256) {
    float ax = xb[m], ay = xb[NPTS + m], az = xb[2 * NPTS + m];
    float sm = sqb[m];
#pragma unroll
    for (int p = 0; p < PPB; ++p) {
      float inner = __fadd_rn(__fadd_rn(__fmul_rn(qx[p], ax), __fmul_rn(qy[p], ay)),
                              __fmul_rn(qz[p], az));
      float d = __fadd_rn(__fsub_rn(qs[p], __fmul_rn(2.0f, inner)), sm);
      int bk = min(NB - 1, (int)(fmaxf(d, 0.f) * 64.0f));
      atomicAdd(&hist[p * NB + bk], 1u);
    }
  }
  __syncthreads();

  // scan: wave wv owns point wv's 1024-bucket hist (16 buckets/lane)
  const int lane = tid & 63, wv = tid >> 6;
  {
    unsigned h[16]; unsigned local = 0;
    const int hb = wv * NB + lane * 16;
#pragma unroll
    for (int j = 0; j < 16; ++j) { h[j] = hist[hb + j]; local += h[j]; }
    unsigned incl = local;
    for (int off = 1; off < 64; off <<= 1) {
      unsigned v = __shfl_up(incl, off, 64);
      if (lane >= off) incl += v;
    }
    unsigned excl = incl - local;
    if (excl < KNN && incl >= KNN) {       // exactly one lane
      unsigned cum = excl;
#pragma unroll
      for (int j = 0; j < 16; ++j) {
        if (cum + h[j] >= KNN) { sB[wv] = lane * 16 + j; break; }
        cum += h[j];
      }
    }
  }
  __syncthreads();

  // pass 2: emit below-boundary, collect boundary candidates
  for (int m = tid; m < NPTS; m += 256) {
    float ax = xb[m], ay = xb[NPTS + m], az = xb[2 * NPTS + m];
    float sm = sqb[m];
#pragma unroll
    for (int p = 0; p < PPB; ++p) {
      float inner = __fadd_rn(__fadd_rn(__fmul_rn(qx[p], ax), __fmul_rn(qy[p], ay)),
                              __fmul_rn(qz[p], az));
      float d = __fadd_rn(__fsub_rn(qs[p], __fmul_rn(2.0f, inner)), sm);
      int bk = min(NB - 1, (int)(fmaxf(d, 0.f) * 64.0f));
      unsigned Bs = sB[p];
      if ((unsigned)bk < Bs) {
        unsigned q = atomicAdd(&sCnt[p], 1u);
        knn_out[((size_t)((b << 12) + n0 + p)) * KNN + q] = m;
      } else if ((unsigned)bk == Bs) {
        unsigned q = atomicAdd(&sCand[p], 1u);
        if (q < CCAP) cand[p * CCAP + q] = (((u64)orderbits(d)) << 32) | (unsigned)m;
      }
    }
  }
  __syncthreads();

  // boundary: wave wv extracts (20 - nsel) smallest (key,idx) of its candidates
  {
    const int nsel = (int)sCnt[wv];
    const int ncand = min((int)sCand[wv], CCAP);
    const int ntake = KNN - nsel;
    const size_t base = ((size_t)((b << 12) + n0 + wv)) * KNN;
    volatile u64* vc = &cand[wv * CCAP];
    for (int t = 0; t < ntake; ++t) {
      u64 mk = ~0ull;
      for (int i = lane; i < ncand; i += 64) { u64 v = vc[i]; if (v < mk) mk = v; }
      for (int off = 32; off; off >>= 1) { u64 o = shflxor64(mk, off); if (o < mk) mk = o; }
      if (lane == 0) knn_out[base + nsel + t] = (int)(unsigned)(mk & 0xffffffffull);
      for (int i = lane; i < ncand; i += 64) { if (vc[i] == mk) vc[i] = ~0ull; }
    }
  }
}

// ---------------- Kernel 2: fused edge MLP 6->64->128 (MFMA) + max over K ---
// 256 thr = 4 waves; 8 points/block. W2 (bf16, pre-converted) staged via LDS
// with chunk-XOR swizzle; B-frags via ds_read_b128 (2-way max = free).
__global__ __launch_bounds__(256, 2) void edge_fused(
    const float* __restrict__ x, const int* __restrict__ knn,
    const float* __restrict__ W1, const float* __restrict__ b1,
    const ushort_t* __restrict__ w2B, const float* __restrict__ b2,
    ushort_t* __restrict__ hT) {
  __shared__ __align__(16) ushort_t h1S[8 * 32 * 64];  // 32 KB
  __shared__ __align__(16) ushort_t w2S[128 * 64];     // 16 KB, swizzled
  const int tid = threadIdx.x;
  const int lane = tid & 63, wv = tid >> 6;
  const int ln = lane & 15, quad = lane >> 4;

  // cooperative W2 stage: 1024 16B-chunks; chunk c of row stored at c^(row&7)
  {
    const int4* wg = (const int4*)w2B;
#pragma unroll
    for (int j = 0; j < 4; ++j) {
      int q = j * 256 + tid;
      int row = q >> 3, c = q & 7;
      ((int4*)w2S)[row * 8 + (c ^ (row & 7))] = wg[q];
    }
  }
  float b2r[8];
#pragma unroll
  for (int n = 0; n < 8; ++n) b2r[n] = b2[n * 16 + ln];

  // ---- stage 1: h1 = relu(W1 @ edge + b1), 2 channels/thread, 20 edges
  {
    const int p = tid >> 5, s5 = tid & 31;
    const int idx = blockIdx.x * 8 + p;
    const int b = idx >> 12, n = idx & 4095;
    const float* xb = x + (size_t)b * 3 * NPTS;
    const float cx = xb[n], cy = xb[NPTS + n], cz = xb[2 * NPTS + n];
    const int c0 = 2 * s5;
    float w1a[6], w1b[6];
#pragma unroll
    for (int j = 0; j < 6; ++j) {
      w1a[j] = W1[c0 * 6 + j];
      w1b[j] = W1[(c0 + 1) * 6 + j];
    }
    const float b1a = b1[c0], b1b = b1[c0 + 1];
    const int kbase = idx * KNN;
    unsigned* h1d = (unsigned*)h1S;
#pragma unroll 4
    for (int k = 0; k < KNN; ++k) {
      int nb = knn[kbase + k];
      float ax = xb[nb], ay = xb[NPTS + nb], az = xb[2 * NPTS + nb];
      float e3 = ax - cx, e4 = ay - cy, e5 = az - cz;
      float za = b1a, zb = b1b;
      za = fmaf(w1a[0], cx, za); zb = fmaf(w1b[0], cx, zb);
      za = fmaf(w1a[1], cy, za); zb = fmaf(w1b[1], cy, zb);
      za = fmaf(w1a[2], cz, za); zb = fmaf(w1b[2], cz, zb);
      za = fmaf(w1a[3], e3, za); zb = fmaf(w1b[3], e3, zb);
      za = fmaf(w1a[4], e4, za); zb = fmaf(w1b[4], e4, zb);
      za = fmaf(w1a[5], e5, za); zb = fmaf(w1b[5], e5, zb);
      unsigned pk = (unsigned)f2bf(fmaxf(za, 0.f)) |
                    ((unsigned)f2bf(fmaxf(zb, 0.f)) << 16);
      int row = p * 32 + k;
      int dw = row * 32 + (((s5 >> 2) ^ (row & 7)) << 2) + (s5 & 3);
      h1d[dw] = pk;
    }
  }
  __syncthreads();

  // B-fragments from swizzled LDS
  bf16x8 Bf[8][2];
#pragma unroll
  for (int n = 0; n < 8; ++n)
#pragma unroll
    for (int s = 0; s < 2; ++s) {
      int row = n * 16 + ln;
      Bf[n][s] = *(const bf16x8*)&w2S[row * 64 + (((s * 4 + quad) ^ (ln & 7)) << 3)];
    }

  // ---- stage 2: per wave, points {2w, 2w+1}; rows 20..31 are garbage -> mask
  const int base_idx = blockIdx.x * 8;
#pragma unroll
  for (int pi = 0; pi < 2; ++pi) {
    const int ps = wv * 2 + pi;
    const int sw = ln & 7;
    float vmax[8];
    {  // tile 0: edge rows 0..15 (all real)
      const int row = ps * 32 + ln;
      bf16x8 A0 = *(const bf16x8*)&h1S[row * 64 + (((0 + quad) ^ sw) << 3)];
      bf16x8 A1 = *(const bf16x8*)&h1S[row * 64 + (((4 + quad) ^ sw) << 3)];
      f32x4 acc;
#pragma unroll
      for (int n = 0; n < 8; ++n) {
        acc = (f32x4){0.f, 0.f, 0.f, 0.f};
        acc = __builtin_amdgcn_mfma_f32_16x16x32_bf16(A0, Bf[n][0], acc, 0, 0, 0);
        acc = __builtin_amdgcn_mfma_f32_16x16x32_bf16(A1, Bf[n][1], acc, 0, 0, 0);
        vmax[n] = fmaxf(fmaxf(acc[0], acc[1]), fmaxf(acc[2], acc[3]));
      }
    }
    {  // tile 1: edge rows 16..31; real only 16..19 => quad==0
      const int row = ps * 32 + 16 + ln;
      bf16x8 A0 = *(const bf16x8*)&h1S[row * 64 + (((0 + quad) ^ sw) << 3)];
      bf16x8 A1 = *(const bf16x8*)&h1S[row * 64 + (((4 + quad) ^ sw) << 3)];
      f32x4 acc;
#pragma unroll
      for (int n = 0; n < 8; ++n) {
        acc = (f32x4){0.f, 0.f, 0.f, 0.f};
        acc = __builtin_amdgcn_mfma_f32_16x16x32_bf16(A0, Bf[n][0], acc, 0, 0, 0);
        acc = __builtin_amdgcn_mfma_f32_16x16x32_bf16(A1, Bf[n][1], acc, 0, 0, 0);
        float v1 = (quad == 0)
                       ? fmaxf(fmaxf(acc[0], acc[1]), fmaxf(acc[2], acc[3]))
                       : -INFINITY;
        vmax[n] = fmaxf(vmax[n], v1);
      }
    }
    const int gidx = base_idx + ps;
#pragma unroll
    for (int n = 0; n < 8; ++n) {
      float v = vmax[n];
      v = fmaxf(v, __shfl_xor(v, 16, 64));
      v = fmaxf(v, __shfl_xor(v, 32, 64));
      if (quad == 0) {
        hT[(size_t)gidx * 128 + n * 16 + ln] = f2bf(fmaxf(v + b2r[n], 0.f));
      }
    }
  }
}

// ---------------- Kernel 2.5: Wi and W2 fp32 -> bf16 ------------------------
__global__ __launch_bounds__(256) void convert_weights(
    const float* __restrict__ Wi, const float* __restrict__ W2,
    ushort_t* __restrict__ wiB, ushort_t* __restrict__ w2B) {
  int i = blockIdx.x * 256 + threadIdx.x;  // 131072 grid
  if (i < 131072) wiB[i] = f2bf(Wi[i]);
  if (i < 8192)   w2B[i] = f2bf(W2[i]);
}

// ---------------- Kernel 3: 128->1024 via bf16 MFMA + relu + max over N -----
#define LDP 136
__global__ __launch_bounds__(256, 2) void inception_mfma(
    const ushort_t* __restrict__ hT, const ushort_t* __restrict__ wiB,
    const float* __restrict__ bi, unsigned* __restrict__ g) {
  __shared__ __align__(16) ushort_t hS[128 * LDP];
  __shared__ __align__(16) ushort_t wS[128 * LDP];
  const int tid = threadIdx.x;
  const int b = blockIdx.z;
  const int m0 = blockIdx.x * 128;
  const int n0 = blockIdx.y * 128;

  const ushort_t* hg = hT + ((size_t)b * NPTS + m0) * 128;
  const ushort_t* wg = wiB + (size_t)n0 * 128;
#pragma unroll
  for (int i = 0; i < 8; ++i) {
    int chunk = i * 256 + tid;
    int row = chunk >> 4, c = chunk & 15;
    *(int4*)&hS[row * LDP + c * 8] = *(const int4*)&hg[row * 128 + c * 8];
    *(int4*)&wS[row * LDP + c * 8] = *(const int4*)&wg[row * 128 + c * 8];
  }
  __syncthreads();

  const int lane = tid & 63, wid = tid >> 6;
  const int ln = lane & 15, quad = lane >> 4;
  const int mw = (wid >> 1) * 64, nw = (wid & 1) * 64;

  f32x4 acc[4][4];
#pragma unroll
  for (int mi = 0; mi < 4; ++mi)
#pragma unroll
    for (int ni = 0; ni < 4; ++ni) acc[mi][ni] = (f32x4){0.f, 0.f, 0.f, 0.f};

#pragma unroll
  for (int kk = 0; kk < 4; ++kk) {
    bf16x8 af[4], bfr[4];
    const int ko = kk * 32 + quad * 8;
#pragma unroll
    for (int mi = 0; mi < 4; ++mi)
      af[mi] = *(const bf16x8*)&hS[(mw + mi * 16 + ln) * LDP + ko];
#pragma unroll
    for (int ni = 0; ni < 4; ++ni)
      bfr[ni] = *(const bf16x8*)&wS[(nw + ni * 16 + ln) * LDP + ko];
#pragma unroll
    for (int mi = 0; mi < 4; ++mi)
#pragma unroll
      for (int ni = 0; ni < 4; ++ni)
        acc[mi][ni] = __builtin_amdgcn_mfma_f32_16x16x32_bf16(
            af[mi], bfr[ni], acc[mi][ni], 0, 0, 0);
  }

#pragma unroll
  for (int ni = 0; ni < 4; ++ni) {
    float v = acc[0][ni][0];
#pragma unroll
    for (int mi = 0; mi < 4; ++mi)
#pragma unroll
      for (int r = 0; r < 4; ++r) v = fmaxf(v, acc[mi][ni][r]);
    v = fmaxf(v, __shfl_xor(v, 16, 64));
    v = fmaxf(v, __shfl_xor(v, 32, 64));
    if (quad == 0) {
      int o = n0 + nw + ni * 16 + ln;
      float val = fmaxf(v + bi[o], 0.f);
      atomicMax(&g[b * 1024 + o], __float_as_uint(val));
    }
  }
}

// ---------------- Kernel 4: head 1024->512->256->9 + I ----------------------
__global__ __launch_bounds__(512) void head_kernel(
    const unsigned* __restrict__ g, const float* __restrict__ Wg1,
    const float* __restrict__ bg1, const float* __restrict__ Wg2,
    const float* __restrict__ bg2, const float* __restrict__ Wl,
    const float* __restrict__ bl, float* __restrict__ out) {
  __shared__ __align__(16) float gl[1024];
  __shared__ __align__(16) float g1l[512];
  __shared__ __align__(16) float g2l[256];
  const int tid = threadIdx.x;
  const int b = blockIdx.x;
  for (int i = tid; i < 1024; i += 512) gl[i] = __uint_as_float(g[b * 1024 + i]);
  __syncthreads();
  {
    const float4* w = (const float4*)(Wg1 + (size_t)tid * 1024);
    const float4* gv = (const float4*)gl;
    float a0 = bg1[tid], a1 = 0.f, a2 = 0.f, a3 = 0.f;
    for (int j = 0; j < 256; j += 4) {
      float4 w0 = w[j], w1 = w[j+1], w2 = w[j+2], w3 = w[j+3];
      float4 v0 = gv[j], v1 = gv[j+1], v2 = gv[j+2], v3 = gv[j+3];
      a0 = fmaf(w0.x, v0.x, a0); a0 = fmaf(w0.y, v0.y, a0);
      a0 = fmaf(w0.z, v0.z, a0); a0 = fmaf(w0.w, v0.w, a0);
      a1 = fmaf(w1.x, v1.x, a1); a1 = fmaf(w1.y, v1.y, a1);
      a1 = fmaf(w1.z, v1.z, a1); a1 = fmaf(w1.w, v1.w, a1);
      a2 = fmaf(w2.x, v2.x, a2); a2 = fmaf(w2.y, v2.y, a2);
      a2 = fmaf(w2.z, v2.z, a2); a2 = fmaf(w2.w, v2.w, a2);
      a3 = fmaf(w3.x, v3.x, a3); a3 = fmaf(w3.y, v3.y, a3);
      a3 = fmaf(w3.z, v3.z, a3); a3 = fmaf(w3.w, v3.w, a3);
    }
    g1l[tid] = fmaxf((a0 + a1) + (a2 + a3), 0.f);
  }
  __syncthreads();
  if (tid < 256) {
    const float4* w = (const float4*)(Wg2 + (size_t)tid * 512);
    const float4* gv = (const float4*)g1l;
    float a0 = bg2[tid], a1 = 0.f;
    for (int j = 0; j < 128; j += 2) {
      float4 w0 = w[j], w1 = w[j+1];
      float4 v0 = gv[j], v1 = gv[j+1];
      a0 = fmaf(w0.x, v0.x, a0); a0 = fmaf(w0.y, v0.y, a0);
      a0 = fmaf(w0.z, v0.z, a0); a0 = fmaf(w0.w, v0.w, a0);
      a1 = fmaf(w1.x, v1.x, a1); a1 = fmaf(w1.y, v1.y, a1);
      a1 = fmaf(w1.z, v1.z, a1); a1 = fmaf(w1.w, v1.w, a1);
    }
    g2l[tid] = fmaxf(a0 + a1, 0.f);
  }
  __syncthreads();
  if (tid < 9) {
    float acc = bl[tid];
    for (int c = 0; c < 256; ++c) acc = fmaf(Wl[tid * 256 + c], g2l[c], acc);
    if (tid == 0 || tid == 4 || tid == 8) acc += 1.0f;
    out[b * 9 + tid] = acc;
  }
}

extern "C" void kernel_launch(void* const* d_in, const int* in_sizes, int n_in,
                              void* d_out, int out_size, void* d_ws, size_t ws_size,
                              hipStream_t stream) {
  const float* x   = (const float*)d_in[0];
  const float* W1  = (const float*)d_in[1];
  const float* b1  = (const float*)d_in[2];
  const float* W2  = (const float*)d_in[3];
  const float* b2  = (const float*)d_in[4];
  const float* Wi  = (const float*)d_in[5];
  const float* bi  = (const float*)d_in[6];
  const float* Wg1 = (const float*)d_in[7];
  const float* bg1 = (const float*)d_in[8];
  const float* Wg2 = (const float*)d_in[9];
  const float* bg2 = (const float*)d_in[10];
  const float* Wl  = (const float*)d_in[11];
  const float* bl  = (const float*)d_in[12];

  int*       knn = (int*)d_ws;                                   // 2.62 MB @ 0
  ushort_t*  hT  = (ushort_t*)((char*)d_ws + (3u << 20));        // 8 MB bf16
  ushort_t*  wiB = (ushort_t*)((char*)d_ws + (12u << 20));       // 256 KB bf16
  ushort_t*  w2B = (ushort_t*)((char*)d_ws + (12u << 20) + (512u << 10)); // 16 KB
  float*     sqg = (float*)((char*)d_ws + (12u << 20) + (768u << 10));    // 128 KB
  unsigned*  g   = (unsigned*)((char*)d_ws + (13u << 20));       // 32 KB

  sq_kernel<<<128, 256, 0, stream>>>(x, sqg);
  knn_kernel<<<8 * NPTS / PPB, 256, 0, stream>>>(x, sqg, knn);
  convert_weights<<<512, 256, 0, stream>>>(Wi, W2, wiB, w2B);
  edge_fused<<<8 * NPTS / 8, 256, 0, stream>>>(x, knn, W1, b1, w2B, b2, hT);
  hipMemsetAsync(g, 0, 8 * 1024 * sizeof(unsigned), stream);
  inception_mfma<<<dim3(32, 8, 8), 256, 0, stream>>>(hT, wiB, bi, g);
  head_kernel<<<8, 512, 0, stream>>>(g, Wg1, bg1, Wg2, bg2, Wl, bl, (float*)d_out);
}